// Round 4
// baseline (150.897 us; speedup 1.0000x reference)
//
#include <hip/hip_runtime.h>

// Problem constants: B=8, C=64, L=32, H=64, W=64
#define BB 8
#define CC 64
#define NSP 131072           // L*H*W = 1<<17 spatial positions per (b,c)
#define PPB 512              // partials per batch (64 channels x 8 sub-blocks)

// ---------------------------------------------------------------------------
// Pipelined fused kernel, launched BB+1 times.
// Dispatch s: blocks [0,512)   -> k1 work for batch b_k1 = s     (sum pass)
//             blocks [512,1024)-> k3 work for batch b_k3 = s - 1 (output pass)
// Reuse distance input-read -> input-re-read = ONE dispatch (~32 MiB), so the
// re-read should hit the 256 MiB Infinity Cache. The two halves overlap HBM
// fresh-reads with HBM writes inside one dispatch.
// mt[b] is reduced per-wave from partials[b] (written one dispatch earlier;
// kernel-boundary release/acquire makes it visible). Deterministic order.
// ---------------------------------------------------------------------------
__global__ __launch_bounds__(256) void k_pipe(
    const float* __restrict__ inpt, const float* __restrict__ theta_w,
    const float* __restrict__ g_w, const float* __restrict__ h_w,
    const float* __restrict__ h_b, float* __restrict__ out,
    float* __restrict__ partials, int b_k1, int b_k3)
{
    if (blockIdx.x < PPB) {
        // ---- k1 half: contiguous streaming sums for batch b_k1 ----
        if (b_k1 >= BB) return;
        int blk = blockIdx.x;                  // 0..511 = c*8+q
        int bc  = (b_k1 << 6) + (blk >> 3);
        int q   = blk & 7;
        const float4* base = reinterpret_cast<const float4*>(inpt)
                             + (((size_t)bc) << 15) + ((size_t)q << 12);
        float4 s4 = make_float4(0.f, 0.f, 0.f, 0.f);
        #pragma unroll
        for (int i = 0; i < 16; ++i) {
            float4 x = base[i * 256 + threadIdx.x];
            s4.x += x.x; s4.y += x.y; s4.z += x.z; s4.w += x.w;
        }
        float s = (s4.x + s4.y) + (s4.z + s4.w);
        #pragma unroll
        for (int off = 32; off > 0; off >>= 1) s += __shfl_down(s, off);
        __shared__ float red[4];
        int wid = threadIdx.x >> 6;
        if ((threadIdx.x & 63) == 0) red[wid] = s;
        __syncthreads();
        if (threadIdx.x == 0)
            partials[(b_k1 << 9) + blk] = (red[0] + red[1]) + (red[2] + red[3]);
    } else {
        // ---- k3 half: fused output pass for batch b_k3 ----
        if (b_k3 < 0) return;
        int blk  = (int)blockIdx.x - PPB;      // 0..511
        int lane = threadIdx.x & 63;

        // per-wave mt reduction: 512 partials, theta-weighted, fixed order
        const float* p = partials + (b_k3 << 9);
        float v = 0.f;
        #pragma unroll
        for (int i = 0; i < 8; ++i) {
            int idx = i * 64 + lane;
            v = fmaf(p[idx], theta_w[idx >> 3], v);
        }
        #pragma unroll
        for (int off = 32; off > 0; off >>= 1) v += __shfl_down(v, off);
        float mt = __shfl(v, 0) * (1.0f / (float)NSP);

        size_t n = ((size_t)blk << 8) + threadIdx.x;            // 0..NSP-1
        const float* base  = inpt + (((size_t)b_k3) << 23) + n; // b*C*NSP
        float vals[CC];
        float gacc = 0.f;
        #pragma unroll
        for (int c = 0; c < CC; ++c) {
            vals[c] = base[((size_t)c) << 17];
            gacc = fmaf(vals[c], g_w[c], gacc);
        }
        float sc = gacc * mt;
        float* obase = out + (((size_t)b_k3) << 23) + n;
        #pragma unroll
        for (int c = 0; c < CC; ++c) {
            float o = fmaf(sc, h_w[c], vals[c] + h_b[c]);
            __builtin_nontemporal_store(o, obase + (((size_t)c) << 17));
        }
    }
}

extern "C" void kernel_launch(void* const* d_in, const int* in_sizes, int n_in,
                              void* d_out, int out_size, void* d_ws, size_t ws_size,
                              hipStream_t stream)
{
    const float* inpt    = (const float*)d_in[0];
    const float* theta_w = (const float*)d_in[1];
    const float* g_w     = (const float*)d_in[2];
    const float* h_w     = (const float*)d_in[3];
    const float* h_b     = (const float*)d_in[4];
    float* out = (float*)d_out;

    float* partials = (float*)d_ws;   // BB * PPB floats = 16 KiB

    for (int s = 0; s <= BB; ++s) {
        hipLaunchKernelGGL(k_pipe, dim3(2 * PPB), dim3(256), 0, stream,
                           inpt, theta_w, g_w, h_w, h_b, out, partials,
                           s, s - 1);
    }
}

// Round 5
// 128.140 us; speedup vs baseline: 1.1776x; 1.1776x over previous
//
#include <hip/hip_runtime.h>

// Problem constants: B=8, C=64, L=32, H=64, W=64
// FINAL (Round-3 revert): 3-dispatch structure at the measured memory roofline.
// Traffic floor: 256 MiB read (mt reduction) + 256 MiB re-read + 256 MiB write
// = 805 MB @ ~7.05 TB/s achieved => ~114 us + k2 + gaps. L3 reuse of the
// second read was disproven in R2 (forward), R3 (reverse), R4 (pipelined).
#define BB 8
#define CC 64
#define NSP 131072           // L*H*W = 1<<17 spatial positions per (b,c)
#define QPB 8                // k1 sub-blocks per (b,c)
#define NPART (BB * CC * QPB)  // 4096 partials

// ---------------------------------------------------------------------------
// k1: pure contiguous streaming sum. Block (b*64+c)*8+q reduces a 64 KiB
// span of channel (b,c). Deterministic tree reduction.
// mt[b] = sum_c theta_w[c] * (sum_n x[b,c,n]) / NSP  -- t[b,n] never formed.
// ---------------------------------------------------------------------------
__global__ __launch_bounds__(256) void k1_sum(
    const float* __restrict__ inpt, float* __restrict__ partials)
{
    int blk = blockIdx.x;                 // 0 .. NPART-1
    int bc = blk >> 3, q = blk & 7;
    const float4* base = reinterpret_cast<const float4*>(inpt)
                         + (((size_t)bc) << 15) + (q << 12);   // 4096-float4 span
    float4 s4 = make_float4(0.f, 0.f, 0.f, 0.f);
    #pragma unroll
    for (int i = 0; i < 16; ++i) {
        float4 x = base[i * 256 + threadIdx.x];
        s4.x += x.x; s4.y += x.y; s4.z += x.z; s4.w += x.w;
    }
    float s = (s4.x + s4.y) + (s4.z + s4.w);
    #pragma unroll
    for (int off = 32; off > 0; off >>= 1) s += __shfl_down(s, off);
    __shared__ float red[4];
    int wid = threadIdx.x >> 6;
    if ((threadIdx.x & 63) == 0) red[wid] = s;
    __syncthreads();
    if (threadIdx.x == 0) partials[blk] = (red[0] + red[1]) + (red[2] + red[3]);
}

// ---------------------------------------------------------------------------
// k2: 8 waves, one per batch. Lane c: sum its 8 partials, scale by theta_w[c],
// wave-reduce over the 64 channels -> mt[b].
// ---------------------------------------------------------------------------
__global__ __launch_bounds__(512) void k2_mt(
    const float* __restrict__ partials, const float* __restrict__ theta_w,
    float* __restrict__ mt)
{
    int b = threadIdx.x >> 6;
    int c = threadIdx.x & 63;
    const float* p = partials + (((b << 6) | c) << 3);
    float v = ((p[0] + p[1]) + (p[2] + p[3])) + ((p[4] + p[5]) + (p[6] + p[7]));
    v *= theta_w[c];
    #pragma unroll
    for (int off = 32; off > 0; off >>= 1) v += __shfl_down(v, off);
    if (c == 0) mt[b] = v * (1.0f / (float)NSP);
}

// ---------------------------------------------------------------------------
// k3: one thread per spatial position, reverse block order (harmless; kept
// from R3). Register-cache all 64 channel values (coalesced dword loads),
// compute g inline, write out = x + (g*mt[b])*h_w[c] + h_b[c] with
// nontemporal stores.
// ---------------------------------------------------------------------------
__global__ __launch_bounds__(256) void k3_fused(
    const float* __restrict__ inpt, const float* __restrict__ g_w,
    const float* __restrict__ mt, const float* __restrict__ h_w,
    const float* __restrict__ h_b, float* __restrict__ out)
{
    int rblk = (int)gridDim.x - 1 - (int)blockIdx.x;      // reverse order
    size_t idx = (size_t)rblk * 256 + threadIdx.x;        // over B*NSP
    int b = (int)(idx >> 17);
    size_t n = idx & (NSP - 1);
    const float* base = inpt + ((((size_t)b) << 6) << 17) + n;

    float vals[CC];
    float gacc = 0.f;
    #pragma unroll
    for (int c = 0; c < CC; ++c) {
        vals[c] = base[((size_t)c) << 17];
        gacc = fmaf(vals[c], g_w[c], gacc);
    }
    float s = gacc * mt[b];
    float* obase = out + ((((size_t)b) << 6) << 17) + n;
    #pragma unroll
    for (int c = 0; c < CC; ++c) {
        float o = fmaf(s, h_w[c], vals[c] + h_b[c]);
        __builtin_nontemporal_store(o, obase + (((size_t)c) << 17));
    }
}

extern "C" void kernel_launch(void* const* d_in, const int* in_sizes, int n_in,
                              void* d_out, int out_size, void* d_ws, size_t ws_size,
                              hipStream_t stream)
{
    const float* inpt    = (const float*)d_in[0];
    const float* theta_w = (const float*)d_in[1];
    const float* g_w     = (const float*)d_in[2];
    const float* h_w     = (const float*)d_in[3];
    const float* h_b     = (const float*)d_in[4];
    float* out = (float*)d_out;

    char* ws = (char*)d_ws;
    float* partials = (float*)ws;                            // 4096 floats
    float* mt       = (float*)(ws + NPART * sizeof(float));  // 8 floats

    hipLaunchKernelGGL(k1_sum, dim3(NPART), dim3(256), 0, stream,
                       inpt, partials);
    hipLaunchKernelGGL(k2_mt, dim3(1), dim3(512), 0, stream,
                       partials, theta_w, mt);
    hipLaunchKernelGGL(k3_fused, dim3((BB * NSP) / 256), dim3(256), 0, stream,
                       inpt, g_w, mt, h_w, h_b, out);
}

// Round 6
// 122.204 us; speedup vs baseline: 1.2348x; 1.0486x over previous
//
#include <hip/hip_runtime.h>

// Problem constants: B=8, C=64, L=32, H=64, W=64
#define BB 8
#define CC 64
#define NSP 131072           // L*H*W = 1<<17 spatial positions per (b,c)
#define QPB 8                // k1 sub-blocks per (b,c)
#define NPART (BB * CC * QPB)  // 4096 partials (512 per batch)

typedef float f2v __attribute__((ext_vector_type(2)));

// ---------------------------------------------------------------------------
// k1: pure contiguous streaming sum. Block (b*64+c)*8+q reduces a 64 KiB
// span of channel (b,c). Deterministic tree reduction.
// ---------------------------------------------------------------------------
__global__ __launch_bounds__(256) void k1_sum(
    const float* __restrict__ inpt, float* __restrict__ partials)
{
    int blk = blockIdx.x;                 // 0 .. NPART-1
    int bc = blk >> 3, q = blk & 7;
    const float4* base = reinterpret_cast<const float4*>(inpt)
                         + (((size_t)bc) << 15) + (q << 12);   // 4096-float4 span
    float4 s4 = make_float4(0.f, 0.f, 0.f, 0.f);
    #pragma unroll
    for (int i = 0; i < 16; ++i) {
        float4 x = base[i * 256 + threadIdx.x];
        s4.x += x.x; s4.y += x.y; s4.z += x.z; s4.w += x.w;
    }
    float s = (s4.x + s4.y) + (s4.z + s4.w);
    #pragma unroll
    for (int off = 32; off > 0; off >>= 1) s += __shfl_down(s, off);
    __shared__ float red[4];
    int wid = threadIdx.x >> 6;
    if ((threadIdx.x & 63) == 0) red[wid] = s;
    __syncthreads();
    if (threadIdx.x == 0) partials[blk] = (red[0] + red[1]) + (red[2] + red[3]);
}

// ---------------------------------------------------------------------------
// k3: fused output pass, float2-vectorized (2 spatial positions per thread).
// Prologue: per-wave mt[b] reduction from the 512 partials of batch b
// (theta-weighted, fixed order -> deterministic; validated in R4).
// Body: register-cache 64 channels as float2 (dwordx2 coalesced loads),
// g inline, out = x + (g*mt)*h_w[c] + h_b[c] via nontemporal dwordx2 stores.
// ---------------------------------------------------------------------------
__global__ __launch_bounds__(256) void k3_fused2(
    const float* __restrict__ inpt, const float* __restrict__ theta_w,
    const float* __restrict__ g_w, const float* __restrict__ h_w,
    const float* __restrict__ h_b, const float* __restrict__ partials,
    float* __restrict__ out)
{
    size_t idx2 = (size_t)blockIdx.x * 256 + threadIdx.x;  // over B*NSP/2
    int b = (int)(idx2 >> 16);
    int lane = threadIdx.x & 63;

    // per-wave mt reduction (all waves of a block share b)
    const float* p = partials + (b << 9);
    float v = 0.f;
    #pragma unroll
    for (int i = 0; i < 8; ++i) {
        int pi = i * 64 + lane;
        v = fmaf(p[pi], theta_w[pi >> 3], v);
    }
    #pragma unroll
    for (int off = 32; off > 0; off >>= 1) v += __shfl_down(v, off);
    float mt = __shfl(v, 0) * (1.0f / (float)NSP);

    size_t n2 = idx2 & 65535;                      // float2 index within (b,c)
    const f2v* base = reinterpret_cast<const f2v*>(inpt)
                      + ((((size_t)b) << 6) << 16) + n2;
    f2v vals[CC];
    float gx = 0.f, gy = 0.f;
    #pragma unroll
    for (int c = 0; c < CC; ++c) {
        vals[c] = base[((size_t)c) << 16];         // channel stride = 65536 f2
        gx = fmaf(vals[c].x, g_w[c], gx);
        gy = fmaf(vals[c].y, g_w[c], gy);
    }
    float sx = gx * mt, sy = gy * mt;
    f2v* obase = reinterpret_cast<f2v*>(out) + ((((size_t)b) << 6) << 16) + n2;
    #pragma unroll
    for (int c = 0; c < CC; ++c) {
        f2v o;
        o.x = fmaf(sx, h_w[c], vals[c].x + h_b[c]);
        o.y = fmaf(sy, h_w[c], vals[c].y + h_b[c]);
        __builtin_nontemporal_store(o, obase + (((size_t)c) << 16));
    }
}

extern "C" void kernel_launch(void* const* d_in, const int* in_sizes, int n_in,
                              void* d_out, int out_size, void* d_ws, size_t ws_size,
                              hipStream_t stream)
{
    const float* inpt    = (const float*)d_in[0];
    const float* theta_w = (const float*)d_in[1];
    const float* g_w     = (const float*)d_in[2];
    const float* h_w     = (const float*)d_in[3];
    const float* h_b     = (const float*)d_in[4];
    float* out = (float*)d_out;

    float* partials = (float*)d_ws;   // 4096 floats

    hipLaunchKernelGGL(k1_sum, dim3(NPART), dim3(256), 0, stream,
                       inpt, partials);
    hipLaunchKernelGGL(k3_fused2, dim3((BB * NSP / 2) / 256), dim3(256), 0, stream,
                       inpt, theta_w, g_w, h_w, h_b, partials, out);
}